// Round 6
// baseline (207.180 us; speedup 1.0000x reference)
//
#include <hip/hip_runtime.h>
#include <hip/hip_bf16.h>

// TopPool: out[b,c,h,w] = max_{h'>=h} x[b,c,h',w]  (reverse cummax over axis 2)
// x shape (32, 256, 128, 128) fp32, w innermost. Compulsory 0.537+0.537 GB.
// R6: float2 column granule. Each wave = 64 lanes x 8 B = exactly one
// contiguous 512 B row (one plane) per load/store; one wave sweeps one plane.
// Halves VGPR footprint (~60) and doubles grid (2048 blocks = 8 blocks/CU =
// 32 waves/CU, full occupancy) for latency cover of the vmcnt drain before
// each store burst. Keeps R4's 2-deep pipeline + nt hints (R5's ascending
// reorder was neutral->negative; reverted).

#define H 128
#define W2 64   // 128 floats / 2 per float2
#define U 8     // h-steps per batch
#define NB (H / U)  // 16 batches

typedef float f32x2 __attribute__((ext_vector_type(2)));

__device__ __forceinline__ f32x2 fmax2(f32x2 a, f32x2 b) {
    f32x2 r;
    r.x = fmaxf(a.x, b.x);
    r.y = fmaxf(a.y, b.y);
    return r;
}

__global__ __launch_bounds__(256) void toppool_kernel(const f32x2* __restrict__ x,
                                                      f32x2* __restrict__ out) {
    const int tid   = blockIdx.x * blockDim.x + threadIdx.x;   // 0 .. 524287
    const int w2    = tid & (W2 - 1);
    const int plane = tid >> 6;                                 // b*C + c

    const size_t base = (size_t)plane * H * W2 + w2;
    const f32x2* xp = x + base;
    f32x2* op = out + base;

    f32x2 cur[U], nxt[U];

    // prologue: load h = 127..120
    #pragma unroll
    for (int i = 0; i < U; ++i)
        cur[i] = __builtin_nontemporal_load(&xp[(H - 1 - i) * W2]);

    f32x2 m;
    m.x = -__builtin_huge_valf();
    m.y = -__builtin_huge_valf();

    // main: batches 0 .. NB-2, each prefetches the following batch first
    for (int b = 0; b < NB - 1; ++b) {
        const int hbase = H - 1 - b * U;
        // issue next batch's loads (independent of the fmax chain)
        #pragma unroll
        for (int i = 0; i < U; ++i)
            nxt[i] = __builtin_nontemporal_load(&xp[(hbase - U - i) * W2]);
        // compute + store current batch
        #pragma unroll
        for (int i = 0; i < U; ++i) {
            m = fmax2(m, cur[i]);
            __builtin_nontemporal_store(m, &op[(hbase - i) * W2]);
        }
        #pragma unroll
        for (int i = 0; i < U; ++i) cur[i] = nxt[i];
    }

    // epilogue: last batch (h = 7..0)
    #pragma unroll
    for (int i = 0; i < U; ++i) {
        m = fmax2(m, cur[i]);
        __builtin_nontemporal_store(m, &op[(U - 1 - i) * W2]);
    }
}

extern "C" void kernel_launch(void* const* d_in, const int* in_sizes, int n_in,
                              void* d_out, int out_size, void* d_ws, size_t ws_size,
                              hipStream_t stream) {
    const f32x2* x = (const f32x2*)d_in[0];
    f32x2* out = (f32x2*)d_out;

    const int total = 32 * 256 * W2;   // 524288 threads
    const int block = 256;
    const int grid = total / block;    // 2048
    toppool_kernel<<<grid, block, 0, stream>>>(x, out);
}